// Round 6
// baseline (275.812 us; speedup 1.0000x reference)
//
#include <hip/hip_runtime.h>
#include <hip/hip_bf16.h>

#define SPA 110592            // D*H*W = 48*48*48
#define NPOS 221184           // B * SPA  (B=2)
#define NELEM 14155776        // B*C*SPA
#define KCODES 256
#define CCH 64
#define PBLK 512              // dw partial blocks (2 per CU exactly)
#define PPOS 432              // positions per dw block (512*432 = NPOS)
#define DWBLK 432             // atomic-fallback grid
#define DWTHR 512
#define EPS_TIE 0.0625f

typedef __attribute__((ext_vector_type(8))) short bf16x8;   // 8 bf16 = 4 VGPRs
typedef __attribute__((ext_vector_type(16))) float f32x16;  // MFMA 32x32 accum

// split fp32 -> bf16 hi (truncate) + bf16 lo (truncate of residual); err ~2^-17|x|
__device__ __forceinline__ void bf16split(float v, short& h, short& l) {
    unsigned bits = __builtin_bit_cast(unsigned, v);
    h = (short)(bits >> 16);
    float hf = __builtin_bit_cast(float, bits & 0xFFFF0000u);
    float res = v - hf;
    l = (short)(__builtin_bit_cast(unsigned, res) >> 16);
}

__device__ __forceinline__ float bf16join(short h, short l) {
    float hf = __builtin_bit_cast(float, ((unsigned)(unsigned short)h) << 16);
    float lf = __builtin_bit_cast(float, ((unsigned)(unsigned short)l) << 16);
    return hf + lf;
}

// pack code index into low 8 mantissa bits of distance; float order preserved
// to within 255 ulp (<< EPS_TIE); exact ordering restored by fp32 rescore.
__device__ __forceinline__ float dpack(float d, int k) {
    unsigned bits = (__builtin_bit_cast(unsigned, d) & 0xFFFFFF00u) | (unsigned)k;
    return __builtin_bit_cast(float, bits);
}
__device__ __forceinline__ int dkey(float d) {
    return (int)(__builtin_bit_cast(unsigned, d) & 0xFFu);
}

// merge two sorted top-2 pairs: result m1' = min, m2' = 2nd smallest of union
__device__ __forceinline__ void top2merge(float& m1, float& m2, float o1, float o2) {
    float a = fminf(m1, o1);
    float b = fmaxf(m1, o1);
    m2 = fminf(b, fminf(m2, o2));
    m1 = a;
}

// ---------------- init: zero accumulators, precompute ||e_k||^2 ----------------
__global__ __launch_bounds__(256) void vq_init(
    const float* __restrict__ emb, float* __restrict__ en2,
    float* __restrict__ dw, float* __restrict__ hist, float* __restrict__ loss)
{
    int t = blockIdx.x * 256 + threadIdx.x;   // 64 blocks
    if (t < CCH * KCODES) dw[t] = 0.f;        // needed by atomic fallback only
    if (t < KCODES) {
        const float* e = emb + (t << 6);
        float s = 0.f;
#pragma unroll
        for (int c = 0; c < CCH; ++c) s = fmaf(e[c], e[c], s);
        en2[t] = s;
        hist[t] = 0.f;
    }
    if (t == 0) loss[0] = 0.f;
}

// ---------------- MFMA argmin ----------------
// 4 waves x 64 codes each; 128 positions/block. Top-2 carried as packed (dist|k)
// floats -> pure fmin/fmax chains, no index regs, half the LDS scratch.
// LDS ~38.6KB + VGPR<=128 -> 4 blocks/CU (16 waves, 50% occ).
__global__ __launch_bounds__(256, 4) void vq_argmin_mfma(
    const float* __restrict__ in, const float* __restrict__ emb,
    const float* __restrict__ en2, float* __restrict__ qout,
    float* __restrict__ encout, float* __restrict__ hist,
    float* __restrict__ loss)
{
    __shared__ __align__(16) short xh[8][128][8];   // 16KB
    __shared__ __align__(16) short xl[8][128][8];   // 16KB
    __shared__ float e2s[KCODES];                   // 1KB
    __shared__ float pm1[4][128], pm2[4][128];      // 4KB (packed dist|k)
    __shared__ int   bestkS[128];                   // 0.5KB
    __shared__ float lhist[KCODES];                 // 1KB
    __shared__ float lred[4];

    int tid  = threadIdx.x;
    int w    = tid >> 6, lane = tid & 63;
    int hi   = lane >> 5, col = lane & 31;
    int wbase = w * 64;

    int blk = blockIdx.x;                 // 1728 blocks; 864 per batch
    int b   = (blk >= 864) ? 1 : 0;
    int s0  = (blk - b * 864) * 128;
    const float* xbase = in + b * (CCH * SPA) + s0;

    if (tid < KCODES) { e2s[tid] = en2[tid]; lhist[tid] = 0.f; }

    // --- resident A fragments: 32-code tiles, lane: row=col, k=hi*8+jj ---
    bf16x8 Ah[2][4], Al[2][4];
#pragma unroll
    for (int ct = 0; ct < 2; ++ct) {
        int code = wbase + ct * 32 + col;
        const float* er = emb + (code << 6) + hi * 8;
#pragma unroll
        for (int j = 0; j < 4; ++j) {
            bf16x8 hfr, lfr;
#pragma unroll
            for (int jj = 0; jj < 8; ++jj) {
                short hs, ls; bf16split(er[j * 16 + jj], hs, ls);
                hfr[jj] = hs; lfr[jj] = ls;
            }
            Ah[ct][j] = hfr; Al[ct][j] = lfr;
        }
    }

    // --- stage x -> LDS bf16 hi/lo; [c>>3][p][c&7] -> b128-clean ---
    {
        int tg = tid >> 7, p = tid & 127;
        const float* xb = xbase + p;
#pragma unroll
        for (int cb = 0; cb < 4; ++cb) {
            int c0 = tg * 32 + cb * 8;
            bf16x8 hfr, lfr;
#pragma unroll
            for (int jj = 0; jj < 8; ++jj) {
                short hs, ls; bf16split(xb[(c0 + jj) * SPA], hs, ls);
                hfr[jj] = hs; lfr[jj] = ls;
            }
            *(bf16x8*)&xh[c0 >> 3][p][0] = hfr;
            *(bf16x8*)&xl[c0 >> 3][p][0] = lfr;
        }
    }
    __syncthreads();

    // --- main MFMA + per-position packed top-2 ---
#pragma unroll 1
    for (int pt = 0; pt < 4; ++pt) {
        int pos = pt * 32 + col;
        f32x16 c0, c1;
#pragma unroll
        for (int i = 0; i < 16; ++i) { c0[i] = 0.f; c1[i] = 0.f; }

#pragma unroll
        for (int j = 0; j < 4; ++j) {
            bf16x8 bh = *(const bf16x8*)&xh[j * 2 + hi][pos][0];
            bf16x8 bl = *(const bf16x8*)&xl[j * 2 + hi][pos][0];
            c0 = __builtin_amdgcn_mfma_f32_32x32x16_bf16(Ah[0][j], bh, c0, 0, 0, 0);
            c1 = __builtin_amdgcn_mfma_f32_32x32x16_bf16(Ah[1][j], bh, c1, 0, 0, 0);
            c0 = __builtin_amdgcn_mfma_f32_32x32x16_bf16(Ah[0][j], bl, c0, 0, 0, 0);
            c1 = __builtin_amdgcn_mfma_f32_32x32x16_bf16(Ah[1][j], bl, c1, 0, 0, 0);
            c0 = __builtin_amdgcn_mfma_f32_32x32x16_bf16(Al[0][j], bh, c0, 0, 0, 0);
            c1 = __builtin_amdgcn_mfma_f32_32x32x16_bf16(Al[1][j], bh, c1, 0, 0, 0);
        }

        // C/D map: col=lane&31, row=(r&3)+8*(r>>2)+4*hi  [m74/m101]
        float m1 = 1e30f, m2 = 1e30f;
#pragma unroll
        for (int ct = 0; ct < 2; ++ct) {
#pragma unroll
            for (int r = 0; r < 16; ++r) {
                int kc  = wbase + ct * 32 + (r & 3) + 8 * (r >> 2) + 4 * hi;
                float d = dpack(fmaf(-2.f, (ct ? c1[r] : c0[r]), e2s[kc]), kc);
                float lo  = fminf(d, m1);
                float hi2 = fmaxf(d, m1);
                m2 = fminf(hi2, m2);
                m1 = lo;
            }
        }
        // merge with partner half-wave (other row half)
        top2merge(m1, m2, __shfl_xor(m1, 32, 64), __shfl_xor(m2, 32, 64));
        if (hi == 0) { pm1[w][pos] = m1; pm2[w][pos] = m2; }
    }
    __syncthreads();

    // --- combine 4 waves' top-2, rescore near-ties exactly in fp32 ---
    if (tid < 128) {
        int p = tid;
        float M1 = pm1[0][p], M2 = pm2[0][p];
#pragma unroll
        for (int ww = 1; ww < 4; ++ww)
            top2merge(M1, M2, pm1[ww][p], pm2[ww][p]);
        int K1 = dkey(M1), K2 = dkey(M2);
        int bk = K1;
        if (M2 <= M1 + EPS_TIE) {      // rare: exact fp32 re-score, ref semantics
            int ka = min(K1, K2), kb = max(K1, K2);
            const float* xb2 = xbase + p;
            const float* ea  = emb + (ka << 6);
            const float* eb2 = emb + (kb << 6);
            float da = 0.f, db = 0.f;
#pragma unroll 4
            for (int c = 0; c < CCH; ++c) {
                float xv = xb2[c * SPA];
                da = fmaf(xv, ea[c], da);
                db = fmaf(xv, eb2[c], db);
            }
            float Da = e2s[ka] - 2.f * da;   // x2 constant, drops out
            float Db = e2s[kb] - 2.f * db;
            bk = (Db < Da) ? kb : ka;        // tie -> lower index (ka)
        }
        bestkS[p] = bk;
        encout[b * SPA + s0 + p] = (float)bk;
        atomicAdd(&lhist[bk], 1.0f);
    }
    __syncthreads();

    // --- quantize write + loss; x reconstructed from LDS hi+lo (err ~2^-17) ---
    {
        int tg = tid >> 7, p = tid & 127;
        int k = bestkS[p];
        const float* ee = emb + (k << 6) + tg * 32;
        float* qp = qout + b * (CCH * SPA) + s0 + p;
        float lsum = 0.f;
#pragma unroll
        for (int cb = 0; cb < 4; ++cb) {
            int oct = tg * 4 + cb;
            bf16x8 hfr = *(const bf16x8*)&xh[oct][p][0];
            bf16x8 lfr = *(const bf16x8*)&xl[oct][p][0];
#pragma unroll
            for (int jj = 0; jj < 8; ++jj) {
                float xv = bf16join(hfr[jj], lfr[jj]);
                float q  = ee[cb * 8 + jj];
                float d  = q - xv;
                lsum = fmaf(d, d, lsum);
                qp[(tg * 32 + cb * 8 + jj) * SPA] = q;
            }
        }
        for (int off = 32; off > 0; off >>= 1) lsum += __shfl_down(lsum, off, 64);
        if (lane == 0) lred[w] = lsum;
    }
    __syncthreads();
    if (tid == 0)
        unsafeAtomicAdd(loss, (lred[0] + lred[1] + lred[2] + lred[3]) * (2.5f / 14155776.f));
    if (tid < KCODES && lhist[tid] != 0.f)
        unsafeAtomicAdd(&hist[tid], lhist[tid]);
}

// ---------------- dw: balanced 512 blocks (2/CU), LDS accumulate -> partials ----------------
__global__ __launch_bounds__(512) void vq_dw_part(
    const float* __restrict__ in, const float* __restrict__ encout,
    float* __restrict__ partial)
{
    __shared__ float l[CCH * KCODES];
    int tid = threadIdx.x;
#pragma unroll
    for (int i = tid; i < CCH * KCODES; i += 512) l[i] = 0.f;
    __syncthreads();

    if (tid < PPOS) {
        int n = blockIdx.x * PPOS + tid;      // contiguous 432-pos chunk
        int b = (n >= SPA) ? 1 : 0;           // SPA = 256*432: clean batch split
        int s = n - b * SPA;
        int k = (int)encout[n];
        const float* xp = in + b * (CCH * SPA) + s;
#pragma unroll
        for (int c = 0; c < CCH; ++c)
            atomicAdd(&l[(c << 8) + (k ^ (c & 31))], xp[c * SPA]);
    }
    __syncthreads();

    float* pp = partial + (size_t)blockIdx.x * (CCH * KCODES);
#pragma unroll
    for (int i = tid; i < CCH * KCODES; i += 512) {
        int k2 = i >> 6, c = i & 63;          // i = k*64 + c -> coalesced stores
        pp[i] = l[(c << 8) + (k2 ^ (c & 31))];
    }
}

__global__ __launch_bounds__(256) void vq_dw_reduce(
    const float* __restrict__ partial, float* __restrict__ dw)
{
    __shared__ float acc[4][64];
    int t = threadIdx.x, lane6 = t & 63, tsub = t >> 6;
    int i = blockIdx.x * 64 + lane6;          // 256 blocks x 64 outputs
    float s = 0.f;
    for (int p = tsub * 128; p < tsub * 128 + 128; ++p)
        s += partial[(size_t)p * (CCH * KCODES) + i];
    acc[tsub][lane6] = s;
    __syncthreads();
    if (tsub == 0)
        dw[i] = (acc[0][lane6] + acc[1][lane6]) + (acc[2][lane6] + acc[3][lane6]);
}

// ---------------- atomic fallback (only if ws too small for partials) ----------------
__global__ __launch_bounds__(DWTHR) void vq_dw_atomic(
    const float* __restrict__ in, const float* __restrict__ encout,
    float* __restrict__ dw)
{
    __shared__ float l[CCH * KCODES];
    int tid = threadIdx.x;
    for (int i = tid; i < CCH * KCODES; i += DWTHR) l[i] = 0.f;
    __syncthreads();
    int n = blockIdx.x * DWTHR + tid;
    int b = (n >= SPA) ? 1 : 0;
    int s = n - b * SPA;
    int k = (int)encout[n];
    const float* xp = in + b * (CCH * SPA) + s;
#pragma unroll
    for (int c = 0; c < CCH; ++c)
        atomicAdd(&l[(c << 8) + (k ^ (c & 31))], xp[c * SPA]);
    __syncthreads();
    for (int i = tid; i < CCH * KCODES; i += DWTHR) {
        int k2 = i >> 6, c = i & 63;
        unsafeAtomicAdd(&dw[i], l[(c << 8) + (k2 ^ (c & 31))]);
    }
}

// ---------------- EMA: weights (1 block), then parallel divide ----------------
__global__ __launch_bounds__(256) void vq_ema_w(
    const float* __restrict__ csize, const float* __restrict__ hist,
    float* __restrict__ wbuf)
{
    __shared__ float red[KCODES];
    int t = threadIdx.x;
    float ncs = 0.99f * csize[t] + 0.01f * hist[t];
    red[t] = ncs;
    __syncthreads();
    for (int off = 128; off > 0; off >>= 1) {
        if (t < off) red[t] += red[t + off];
        __syncthreads();
    }
    float nsum = red[0];
    wbuf[t] = (ncs + 1e-5f) / (nsum + 256.f * 1e-5f) * nsum;
}

__global__ __launch_bounds__(256) void vq_emb(
    const float* __restrict__ emaw, const float* __restrict__ dw,
    const float* __restrict__ wbuf, float* __restrict__ embo)
{
    int i = blockIdx.x * 256 + threadIdx.x;   // 64 blocks
    float nw = fmaf(0.01f, dw[i], 0.99f * emaw[i]);
    embo[i] = nw / wbuf[i >> 6];
}

extern "C" void kernel_launch(void* const* d_in, const int* in_sizes, int n_in,
                              void* d_out, int out_size, void* d_ws, size_t ws_size,
                              hipStream_t stream)
{
    const float* in   = (const float*)d_in[0];
    const float* emb  = (const float*)d_in[1];
    const float* cs   = (const float*)d_in[2];
    const float* emaw = (const float*)d_in[3];

    float* out  = (float*)d_out;
    float* qout = out;                         // 14,155,776
    float* loss = out + NELEM;                 // 1
    float* enc  = loss + 1;                    // 221,184
    float* hist = enc + NPOS;                  // 256  (encodings_sum output)
    float* embo = hist + KCODES;               // 16,384

    float* en2     = (float*)d_ws;             // 256
    float* wbuf    = en2 + KCODES;             // 256
    float* dw      = wbuf + KCODES;            // 16,384
    float* partial = dw + CCH * KCODES;        // 512 * 16,384

    size_t need = (size_t)(2 * KCODES + CCH * KCODES) * 4
                + (size_t)PBLK * CCH * KCODES * 4;
    bool use_part = (ws_size >= need);         // constant per session -> graph-safe

    vq_init<<<dim3(64), dim3(256), 0, stream>>>(emb, en2, dw, hist, loss);
    vq_argmin_mfma<<<dim3(1728), dim3(256), 0, stream>>>(in, emb, en2, qout, enc, hist, loss);
    if (use_part) {
        vq_dw_part<<<dim3(PBLK), dim3(512), 0, stream>>>(in, enc, partial);
        vq_dw_reduce<<<dim3(256), dim3(256), 0, stream>>>(partial, dw);
    } else {
        vq_dw_atomic<<<dim3(DWBLK), dim3(DWTHR), 0, stream>>>(in, enc, dw);
    }
    vq_ema_w<<<dim3(1), dim3(256), 0, stream>>>(cs, hist, wbuf);
    vq_emb<<<dim3(64), dim3(256), 0, stream>>>(emaw, dw, wbuf, embo);
}

// Round 7
// 274.514 us; speedup vs baseline: 1.0047x; 1.0047x over previous
//
#include <hip/hip_runtime.h>
#include <hip/hip_bf16.h>

#define SPA 110592            // D*H*W = 48*48*48
#define NPOS 221184           // B * SPA  (B=2)
#define NELEM 14155776        // B*C*SPA
#define KCODES 256
#define CCH 64
#define NPART 256             // dw partial copies (1 block/CU exactly)
#define PPB 864               // positions per dw block (256*864 = NPOS)
#define DWBLK 432             // atomic-fallback grid
#define DWTHR 512
#define EPS_TIE 0.0625f

typedef __attribute__((ext_vector_type(8))) short bf16x8;   // 8 bf16 = 4 VGPRs
typedef __attribute__((ext_vector_type(16))) float f32x16;  // MFMA 32x32 accum

// split fp32 -> bf16 hi (truncate) + bf16 lo (truncate of residual); err ~2^-17|x|
__device__ __forceinline__ void bf16split(float v, short& h, short& l) {
    unsigned bits = __builtin_bit_cast(unsigned, v);
    h = (short)(bits >> 16);
    float hf = __builtin_bit_cast(float, bits & 0xFFFF0000u);
    float res = v - hf;
    l = (short)(__builtin_bit_cast(unsigned, res) >> 16);
}

__device__ __forceinline__ float bf16join(short h, short l) {
    float hf = __builtin_bit_cast(float, ((unsigned)(unsigned short)h) << 16);
    float lf = __builtin_bit_cast(float, ((unsigned)(unsigned short)l) << 16);
    return hf + lf;
}

// pack code index into low 8 mantissa bits of distance; order preserved to
// ~256 ulp (<< EPS_TIE); exact ordering restored by fp32 rescore on ties.
__device__ __forceinline__ float dpack(float d, int k) {
    unsigned bits = (__builtin_bit_cast(unsigned, d) & 0xFFFFFF00u) | (unsigned)k;
    return __builtin_bit_cast(float, bits);
}
__device__ __forceinline__ int dkey(float d) {
    return (int)(__builtin_bit_cast(unsigned, d) & 0xFFu);
}

// merge two sorted top-2 pairs
__device__ __forceinline__ void top2merge(float& m1, float& m2, float o1, float o2) {
    float a = fminf(m1, o1);
    float b = fmaxf(m1, o1);
    m2 = fminf(b, fminf(m2, o2));
    m1 = a;
}

// ---------------- init: zero dw, build A-fragments, ||e||^2, zero hist/loss ----------------
// Fragment layout (lane-coalesced): group g = w*8 + ct*4 + j (32 groups), lane 0..63.
// fragH[g*64+lane] = bf16x8 of channels {(lane>>5)*8 + j*16 + jj} of code w*64+ct*32+(lane&31).
__global__ __launch_bounds__(256) void vq_init(
    const float* __restrict__ emb, float* __restrict__ en2,
    float* __restrict__ dw, float* __restrict__ hist, float* __restrict__ loss,
    float* __restrict__ fragH, float* __restrict__ fragL)
{
    int t = blockIdx.x * 256 + threadIdx.x;   // 64 blocks = 16384 threads
    if (t < CCH * KCODES) dw[t] = 0.f;        // used by atomic fallback only
    if (t < 2048) {                           // fragment builder
        int g = t >> 6, lane = t & 63;
        int w = g >> 3, ct = (g >> 2) & 1, j = g & 3;
        int code = w * 64 + ct * 32 + (lane & 31);
        int ch0 = (lane >> 5) * 8 + j * 16;
        const float* er = emb + (code << 6) + ch0;
        bf16x8 hfr, lfr;
#pragma unroll
        for (int jj = 0; jj < 8; ++jj) {
            short hs, ls; bf16split(er[jj], hs, ls);
            hfr[jj] = hs; lfr[jj] = ls;
        }
        ((bf16x8*)fragH)[t] = hfr;
        ((bf16x8*)fragL)[t] = lfr;
    }
    if (t >= 2048 && t < 4096) {              // ||e_k||^2, 8 lanes per code
        int t2 = t - 2048;
        int code = t2 >> 3, seg = t2 & 7;
        const float* e = emb + (code << 6) + seg * 8;
        float s = 0.f;
#pragma unroll
        for (int jj = 0; jj < 8; ++jj) s = fmaf(e[jj], e[jj], s);
        s += __shfl_down(s, 4, 64);
        s += __shfl_down(s, 2, 64);
        s += __shfl_down(s, 1, 64);
        if (seg == 0) en2[code] = s;
    }
    if (t < KCODES) hist[t] = 0.f;
    if (t == 0) loss[0] = 0.f;
}

// ---------------- MFMA argmin ----------------
// 4 waves x 64 codes; 128 positions/block. A-fragments loaded via 16 coalesced
// b128 reads of the precomputed layout (L2-hot, replaces 512 divergent gathers).
// (256,3): VGPR cap 170 -> resident frags fit WITHOUT spill (r6's (256,4) spilled).
__global__ __launch_bounds__(256, 3) void vq_argmin_mfma(
    const float* __restrict__ in, const float* __restrict__ emb,
    const float* __restrict__ en2, const float* __restrict__ fragH,
    const float* __restrict__ fragL, float* __restrict__ qout,
    float* __restrict__ encout, float* __restrict__ hist,
    float* __restrict__ loss)
{
    __shared__ __align__(16) short xh[8][128][8];   // 16KB
    __shared__ __align__(16) short xl[8][128][8];   // 16KB
    __shared__ float e2s[KCODES];                   // 1KB
    __shared__ float pm1[4][128], pm2[4][128];      // 4KB (packed dist|k)
    __shared__ int   bestkS[128];
    __shared__ float lhist[KCODES];
    __shared__ float lred[4];

    int tid  = threadIdx.x;
    int w    = tid >> 6, lane = tid & 63;
    int hi   = lane >> 5, col = lane & 31;
    int wbase = w * 64;

    int blk = blockIdx.x;                 // 1728 blocks; 864 per batch
    int b   = (blk >= 864) ? 1 : 0;
    int s0  = (blk - b * 864) * 128;
    const float* xbase = in + b * (CCH * SPA) + s0;

    if (tid < KCODES) { e2s[tid] = en2[tid]; lhist[tid] = 0.f; }

    // --- resident A fragments: 16 coalesced b128 loads ---
    const bf16x8* fH = (const bf16x8*)fragH;
    const bf16x8* fL = (const bf16x8*)fragL;
    bf16x8 Ah[2][4], Al[2][4];
#pragma unroll
    for (int ct = 0; ct < 2; ++ct)
#pragma unroll
        for (int j = 0; j < 4; ++j) {
            int g = (w * 8 + ct * 4 + j) * 64 + lane;
            Ah[ct][j] = fH[g];
            Al[ct][j] = fL[g];
        }

    // --- stage x -> LDS bf16 hi/lo; [c>>3][p][c&7] -> b128-clean ---
    {
        int tg = tid >> 7, p = tid & 127;
        const float* xb = xbase + p;
#pragma unroll
        for (int cb = 0; cb < 4; ++cb) {
            int c0 = tg * 32 + cb * 8;
            bf16x8 hfr, lfr;
#pragma unroll
            for (int jj = 0; jj < 8; ++jj) {
                short hs, ls; bf16split(xb[(c0 + jj) * SPA], hs, ls);
                hfr[jj] = hs; lfr[jj] = ls;
            }
            *(bf16x8*)&xh[c0 >> 3][p][0] = hfr;
            *(bf16x8*)&xl[c0 >> 3][p][0] = lfr;
        }
    }
    __syncthreads();

    // --- main MFMA + per-position packed top-2 ---
#pragma unroll 1
    for (int pt = 0; pt < 4; ++pt) {
        int pos = pt * 32 + col;
        f32x16 c0, c1;
#pragma unroll
        for (int i = 0; i < 16; ++i) { c0[i] = 0.f; c1[i] = 0.f; }

#pragma unroll
        for (int j = 0; j < 4; ++j) {
            bf16x8 bh = *(const bf16x8*)&xh[j * 2 + hi][pos][0];
            bf16x8 bl = *(const bf16x8*)&xl[j * 2 + hi][pos][0];
            c0 = __builtin_amdgcn_mfma_f32_32x32x16_bf16(Ah[0][j], bh, c0, 0, 0, 0);
            c1 = __builtin_amdgcn_mfma_f32_32x32x16_bf16(Ah[1][j], bh, c1, 0, 0, 0);
            c0 = __builtin_amdgcn_mfma_f32_32x32x16_bf16(Ah[0][j], bl, c0, 0, 0, 0);
            c1 = __builtin_amdgcn_mfma_f32_32x32x16_bf16(Ah[1][j], bl, c1, 0, 0, 0);
            c0 = __builtin_amdgcn_mfma_f32_32x32x16_bf16(Al[0][j], bh, c0, 0, 0, 0);
            c1 = __builtin_amdgcn_mfma_f32_32x32x16_bf16(Al[1][j], bh, c1, 0, 0, 0);
        }

        // C/D map: col=lane&31, row=(r&3)+8*(r>>2)+4*hi  [m74/m101]
        float m1 = 1e30f, m2 = 1e30f;
#pragma unroll
        for (int ct = 0; ct < 2; ++ct) {
#pragma unroll
            for (int r = 0; r < 16; ++r) {
                int kc  = wbase + ct * 32 + (r & 3) + 8 * (r >> 2) + 4 * hi;
                float d = dpack(fmaf(-2.f, (ct ? c1[r] : c0[r]), e2s[kc]), kc);
                float lo  = fminf(d, m1);
                float hi2 = fmaxf(d, m1);
                m2 = fminf(hi2, m2);
                m1 = lo;
            }
        }
        top2merge(m1, m2, __shfl_xor(m1, 32, 64), __shfl_xor(m2, 32, 64));
        if (hi == 0) { pm1[w][pos] = m1; pm2[w][pos] = m2; }
    }
    __syncthreads();

    // --- combine 4 waves' top-2, rescore near-ties exactly in fp32 ---
    if (tid < 128) {
        int p = tid;
        float M1 = pm1[0][p], M2 = pm2[0][p];
#pragma unroll
        for (int ww = 1; ww < 4; ++ww)
            top2merge(M1, M2, pm1[ww][p], pm2[ww][p]);
        int K1 = dkey(M1), K2 = dkey(M2);
        int bk = K1;
        if (M2 <= M1 + EPS_TIE) {      // rare: exact fp32 re-score, ref semantics
            int ka = min(K1, K2), kb = max(K1, K2);
            const float* xb2 = xbase + p;
            const float* ea  = emb + (ka << 6);
            const float* eb2 = emb + (kb << 6);
            float da = 0.f, db = 0.f;
#pragma unroll 4
            for (int c = 0; c < CCH; ++c) {
                float xv = xb2[c * SPA];
                da = fmaf(xv, ea[c], da);
                db = fmaf(xv, eb2[c], db);
            }
            float Da = e2s[ka] - 2.f * da;   // x2 identical for both, drops out
            float Db = e2s[kb] - 2.f * db;
            bk = (Db < Da) ? kb : ka;        // tie -> lower index
        }
        bestkS[p] = bk;
        encout[b * SPA + s0 + p] = (float)bk;
        atomicAdd(&lhist[bk], 1.0f);
    }
    __syncthreads();

    // --- quantize write + loss; x reconstructed from LDS hi+lo (err ~2^-17) ---
    {
        int tg = tid >> 7, p = tid & 127;
        int k = bestkS[p];
        const float* ee = emb + (k << 6) + tg * 32;
        float* qp = qout + b * (CCH * SPA) + s0 + p;
        float lsum = 0.f;
#pragma unroll
        for (int cb = 0; cb < 4; ++cb) {
            int oct = tg * 4 + cb;
            bf16x8 hfr = *(const bf16x8*)&xh[oct][p][0];
            bf16x8 lfr = *(const bf16x8*)&xl[oct][p][0];
#pragma unroll
            for (int jj = 0; jj < 8; ++jj) {
                float xv = bf16join(hfr[jj], lfr[jj]);
                float q  = ee[cb * 8 + jj];
                float d  = q - xv;
                lsum = fmaf(d, d, lsum);
                qp[(tg * 32 + cb * 8 + jj) * SPA] = q;
            }
        }
        for (int off = 32; off > 0; off >>= 1) lsum += __shfl_down(lsum, off, 64);
        if (lane == 0) lred[w] = lsum;
    }
    __syncthreads();
    if (tid == 0)
        unsafeAtomicAdd(loss, (lred[0] + lred[1] + lred[2] + lred[3]) * (2.5f / 14155776.f));
    if (tid < KCODES && lhist[tid] != 0.f)
        unsafeAtomicAdd(&hist[tid], lhist[tid]);
}

// ---------------- dw: 256 blocks (1/CU), 864 pos each, LDS accumulate -> partials ----------------
__global__ __launch_bounds__(512) void vq_dw_part(
    const float* __restrict__ in, const float* __restrict__ encout,
    float* __restrict__ partial)
{
    __shared__ float l[CCH * KCODES];
    int tid = threadIdx.x;
#pragma unroll
    for (int i = tid; i < CCH * KCODES; i += 512) l[i] = 0.f;
    __syncthreads();

    int base = blockIdx.x * PPB;              // blocks never straddle batches
    int b    = (blockIdx.x >= 128) ? 1 : 0;   // 128*864 = SPA
    {
        int n = base + tid;
        int s = n - b * SPA;
        int k = (int)encout[n];
        const float* xp = in + b * (CCH * SPA) + s;
#pragma unroll
        for (int c = 0; c < CCH; ++c)
            atomicAdd(&l[(c << 8) + (k ^ (c & 31))], xp[c * SPA]);
    }
    if (tid < PPB - 512) {                    // second position (352 threads)
        int n = base + 512 + tid;
        int s = n - b * SPA;
        int k = (int)encout[n];
        const float* xp = in + b * (CCH * SPA) + s;
#pragma unroll
        for (int c = 0; c < CCH; ++c)
            atomicAdd(&l[(c << 8) + (k ^ (c & 31))], xp[c * SPA]);
    }
    __syncthreads();

    float* pp = partial + (size_t)blockIdx.x * (CCH * KCODES);
#pragma unroll
    for (int i = tid; i < CCH * KCODES; i += 512) {
        int k2 = i >> 6, c = i & 63;          // i = k*64 + c -> coalesced stores
        pp[i] = l[(c << 8) + (k2 ^ (c & 31))];
    }
}

__global__ __launch_bounds__(256) void vq_dw_reduce(
    const float* __restrict__ partial, float* __restrict__ dw)
{
    __shared__ float acc[4][64];
    int t = threadIdx.x, lane6 = t & 63, tsub = t >> 6;
    int i = blockIdx.x * 64 + lane6;          // 256 blocks x 64 outputs
    float s = 0.f;
    for (int p = tsub * 64; p < tsub * 64 + 64; ++p)
        s += partial[(size_t)p * (CCH * KCODES) + i];
    acc[tsub][lane6] = s;
    __syncthreads();
    if (tsub == 0)
        dw[i] = (acc[0][lane6] + acc[1][lane6]) + (acc[2][lane6] + acc[3][lane6]);
}

// ---------------- atomic fallback (only if ws too small for partials) ----------------
__global__ __launch_bounds__(DWTHR) void vq_dw_atomic(
    const float* __restrict__ in, const float* __restrict__ encout,
    float* __restrict__ dw)
{
    __shared__ float l[CCH * KCODES];
    int tid = threadIdx.x;
    for (int i = tid; i < CCH * KCODES; i += DWTHR) l[i] = 0.f;
    __syncthreads();
    int n = blockIdx.x * DWTHR + tid;
    int b = (n >= SPA) ? 1 : 0;
    int s = n - b * SPA;
    int k = (int)encout[n];
    const float* xp = in + b * (CCH * SPA) + s;
#pragma unroll
    for (int c = 0; c < CCH; ++c)
        atomicAdd(&l[(c << 8) + (k ^ (c & 31))], xp[c * SPA]);
    __syncthreads();
    for (int i = tid; i < CCH * KCODES; i += DWTHR) {
        int k2 = i >> 6, c = i & 63;
        unsafeAtomicAdd(&dw[i], l[(c << 8) + (k2 ^ (c & 31))]);
    }
}

// ---------------- EMA finalize, fused: weights + divide ----------------
__global__ __launch_bounds__(1024) void vq_ema(
    const float* __restrict__ csize, const float* __restrict__ emaw,
    const float* __restrict__ hist, const float* __restrict__ dw,
    float* __restrict__ embo)
{
    __shared__ float red[KCODES];
    __shared__ float wsm[KCODES];
    int t = threadIdx.x;
    float ncs = 0.f;
    if (t < KCODES) { ncs = 0.99f * csize[t] + 0.01f * hist[t]; red[t] = ncs; }
    __syncthreads();
    for (int off = 128; off > 0; off >>= 1) {
        if (t < off) red[t] += red[t + off];
        __syncthreads();
    }
    float nsum = red[0];
    if (t < KCODES) wsm[t] = (ncs + 1e-5f) / (nsum + 256.f * 1e-5f) * nsum;
    __syncthreads();
    for (int i = t; i < CCH * KCODES; i += 1024) {
        float nw = fmaf(0.01f, dw[i], 0.99f * emaw[i]);
        embo[i] = nw / wsm[i >> 6];
    }
}

extern "C" void kernel_launch(void* const* d_in, const int* in_sizes, int n_in,
                              void* d_out, int out_size, void* d_ws, size_t ws_size,
                              hipStream_t stream)
{
    const float* in   = (const float*)d_in[0];
    const float* emb  = (const float*)d_in[1];
    const float* cs   = (const float*)d_in[2];
    const float* emaw = (const float*)d_in[3];

    float* out  = (float*)d_out;
    float* qout = out;                         // 14,155,776
    float* loss = out + NELEM;                 // 1
    float* enc  = loss + 1;                    // 221,184
    float* hist = enc + NPOS;                  // 256  (encodings_sum output)
    float* embo = hist + KCODES;               // 16,384

    float* en2     = (float*)d_ws;             // 256
    float* dw      = en2 + KCODES;             // 16,384
    float* fragH   = dw + CCH * KCODES;        // 8,192 (32KB of bf16x8)
    float* fragL   = fragH + 8192;             // 8,192
    float* partial = fragL + 8192;             // 256 * 16,384

    size_t need = (size_t)(KCODES + CCH * KCODES + 16384) * 4
                + (size_t)NPART * CCH * KCODES * 4;
    bool use_part = (ws_size >= need);         // constant per session -> graph-safe

    vq_init<<<dim3(64), dim3(256), 0, stream>>>(emb, en2, dw, hist, loss, fragH, fragL);
    vq_argmin_mfma<<<dim3(1728), dim3(256), 0, stream>>>(in, emb, en2, fragH, fragL,
                                                         qout, enc, hist, loss);
    if (use_part) {
        vq_dw_part<<<dim3(NPART), dim3(512), 0, stream>>>(in, enc, partial);
        vq_dw_reduce<<<dim3(256), dim3(256), 0, stream>>>(partial, dw);
    } else {
        vq_dw_atomic<<<dim3(DWBLK), dim3(DWTHR), 0, stream>>>(in, enc, dw);
    }
    vq_ema<<<dim3(1), dim3(1024), 0, stream>>>(cs, emaw, hist, dw, embo);
}

// Round 8
// 238.135 us; speedup vs baseline: 1.1582x; 1.1528x over previous
//
#include <hip/hip_runtime.h>
#include <hip/hip_bf16.h>

#define SPA 110592            // D*H*W = 48*48*48
#define NPOS 221184           // B * SPA  (B=2)
#define NELEM 14155776        // B*C*SPA
#define KCODES 256
#define CCH 64
#define DWG 432               // dw-mfma blocks: 432 * 512 pos = NPOS
#define DWCHUNK 128           // positions per staged chunk (4 chunks/block)
#define DWBLK 432             // atomic-fallback grid
#define DWTHR 512
#define EPS_TIE 0.0625f

typedef __attribute__((ext_vector_type(8))) short bf16x8;   // 8 bf16 = 4 VGPRs
typedef __attribute__((ext_vector_type(16))) float f32x16;  // MFMA 32x32 accum

// split fp32 -> bf16 hi (truncate) + bf16 lo (truncate of residual); err ~2^-17|x|
__device__ __forceinline__ void bf16split(float v, short& h, short& l) {
    unsigned bits = __builtin_bit_cast(unsigned, v);
    h = (short)(bits >> 16);
    float hf = __builtin_bit_cast(float, bits & 0xFFFF0000u);
    float res = v - hf;
    l = (short)(__builtin_bit_cast(unsigned, res) >> 16);
}

__device__ __forceinline__ float bf16join(short h, short l) {
    float hf = __builtin_bit_cast(float, ((unsigned)(unsigned short)h) << 16);
    float lf = __builtin_bit_cast(float, ((unsigned)(unsigned short)l) << 16);
    return hf + lf;
}

// pack code index into low 8 mantissa bits of distance; order preserved to
// ~256 ulp (<< EPS_TIE); exact ordering restored by fp32 rescore on ties.
__device__ __forceinline__ float dpack(float d, int k) {
    unsigned bits = (__builtin_bit_cast(unsigned, d) & 0xFFFFFF00u) | (unsigned)k;
    return __builtin_bit_cast(float, bits);
}
__device__ __forceinline__ int dkey(float d) {
    return (int)(__builtin_bit_cast(unsigned, d) & 0xFFu);
}

__device__ __forceinline__ void top2merge(float& m1, float& m2, float o1, float o2) {
    float a = fminf(m1, o1);
    float b = fmaxf(m1, o1);
    m2 = fminf(b, fminf(m2, o2));
    m1 = a;
}

// ---------------- init: zero dw, build A-fragments, ||e||^2, zero hist/loss ----------------
__global__ __launch_bounds__(256) void vq_init(
    const float* __restrict__ emb, float* __restrict__ en2,
    float* __restrict__ dw, float* __restrict__ hist, float* __restrict__ loss,
    float* __restrict__ fragH, float* __restrict__ fragL)
{
    int t = blockIdx.x * 256 + threadIdx.x;   // 64 blocks = 16384 threads
    if (t < CCH * KCODES) dw[t] = 0.f;        // used by atomic fallback only
    if (t < 2048) {                           // argmin A-fragment builder
        int g = t >> 6, lane = t & 63;
        int w = g >> 3, ct = (g >> 2) & 1, j = g & 3;
        int code = w * 64 + ct * 32 + (lane & 31);
        int ch0 = (lane >> 5) * 8 + j * 16;
        const float* er = emb + (code << 6) + ch0;
        bf16x8 hfr, lfr;
#pragma unroll
        for (int jj = 0; jj < 8; ++jj) {
            short hs, ls; bf16split(er[jj], hs, ls);
            hfr[jj] = hs; lfr[jj] = ls;
        }
        ((bf16x8*)fragH)[t] = hfr;
        ((bf16x8*)fragL)[t] = lfr;
    }
    if (t >= 2048 && t < 4096) {              // ||e_k||^2, 8 lanes per code
        int t2 = t - 2048;
        int code = t2 >> 3, seg = t2 & 7;
        const float* e = emb + (code << 6) + seg * 8;
        float s = 0.f;
#pragma unroll
        for (int jj = 0; jj < 8; ++jj) s = fmaf(e[jj], e[jj], s);
        s += __shfl_down(s, 4, 64);
        s += __shfl_down(s, 2, 64);
        s += __shfl_down(s, 1, 64);
        if (seg == 0) en2[code] = s;
    }
    if (t < KCODES) hist[t] = 0.f;
    if (t == 0) loss[0] = 0.f;
}

// ---------------- MFMA argmin (unchanged from round 7) ----------------
__global__ __launch_bounds__(256, 3) void vq_argmin_mfma(
    const float* __restrict__ in, const float* __restrict__ emb,
    const float* __restrict__ en2, const float* __restrict__ fragH,
    const float* __restrict__ fragL, float* __restrict__ qout,
    float* __restrict__ encout, float* __restrict__ hist,
    float* __restrict__ loss)
{
    __shared__ __align__(16) short xh[8][128][8];   // 16KB
    __shared__ __align__(16) short xl[8][128][8];   // 16KB
    __shared__ float e2s[KCODES];
    __shared__ float pm1[4][128], pm2[4][128];
    __shared__ int   bestkS[128];
    __shared__ float lhist[KCODES];
    __shared__ float lred[4];

    int tid  = threadIdx.x;
    int w    = tid >> 6, lane = tid & 63;
    int hi   = lane >> 5, col = lane & 31;
    int wbase = w * 64;

    int blk = blockIdx.x;                 // 1728 blocks; 864 per batch
    int b   = (blk >= 864) ? 1 : 0;
    int s0  = (blk - b * 864) * 128;
    const float* xbase = in + b * (CCH * SPA) + s0;

    if (tid < KCODES) { e2s[tid] = en2[tid]; lhist[tid] = 0.f; }

    const bf16x8* fH = (const bf16x8*)fragH;
    const bf16x8* fL = (const bf16x8*)fragL;
    bf16x8 Ah[2][4], Al[2][4];
#pragma unroll
    for (int ct = 0; ct < 2; ++ct)
#pragma unroll
        for (int j = 0; j < 4; ++j) {
            int g = (w * 8 + ct * 4 + j) * 64 + lane;
            Ah[ct][j] = fH[g];
            Al[ct][j] = fL[g];
        }

    {
        int tg = tid >> 7, p = tid & 127;
        const float* xb = xbase + p;
#pragma unroll
        for (int cb = 0; cb < 4; ++cb) {
            int c0 = tg * 32 + cb * 8;
            bf16x8 hfr, lfr;
#pragma unroll
            for (int jj = 0; jj < 8; ++jj) {
                short hs, ls; bf16split(xb[(c0 + jj) * SPA], hs, ls);
                hfr[jj] = hs; lfr[jj] = ls;
            }
            *(bf16x8*)&xh[c0 >> 3][p][0] = hfr;
            *(bf16x8*)&xl[c0 >> 3][p][0] = lfr;
        }
    }
    __syncthreads();

#pragma unroll 1
    for (int pt = 0; pt < 4; ++pt) {
        int pos = pt * 32 + col;
        f32x16 c0, c1;
#pragma unroll
        for (int i = 0; i < 16; ++i) { c0[i] = 0.f; c1[i] = 0.f; }

#pragma unroll
        for (int j = 0; j < 4; ++j) {
            bf16x8 bh = *(const bf16x8*)&xh[j * 2 + hi][pos][0];
            bf16x8 bl = *(const bf16x8*)&xl[j * 2 + hi][pos][0];
            c0 = __builtin_amdgcn_mfma_f32_32x32x16_bf16(Ah[0][j], bh, c0, 0, 0, 0);
            c1 = __builtin_amdgcn_mfma_f32_32x32x16_bf16(Ah[1][j], bh, c1, 0, 0, 0);
            c0 = __builtin_amdgcn_mfma_f32_32x32x16_bf16(Ah[0][j], bl, c0, 0, 0, 0);
            c1 = __builtin_amdgcn_mfma_f32_32x32x16_bf16(Ah[1][j], bl, c1, 0, 0, 0);
            c0 = __builtin_amdgcn_mfma_f32_32x32x16_bf16(Al[0][j], bh, c0, 0, 0, 0);
            c1 = __builtin_amdgcn_mfma_f32_32x32x16_bf16(Al[1][j], bh, c1, 0, 0, 0);
        }

        // C/D map: col=lane&31, row=(r&3)+8*(r>>2)+4*hi  [m74/m101]
        float m1 = 1e30f, m2 = 1e30f;
#pragma unroll
        for (int ct = 0; ct < 2; ++ct) {
#pragma unroll
            for (int r = 0; r < 16; ++r) {
                int kc  = wbase + ct * 32 + (r & 3) + 8 * (r >> 2) + 4 * hi;
                float d = dpack(fmaf(-2.f, (ct ? c1[r] : c0[r]), e2s[kc]), kc);
                float lo  = fminf(d, m1);
                float hi2 = fmaxf(d, m1);
                m2 = fminf(hi2, m2);
                m1 = lo;
            }
        }
        top2merge(m1, m2, __shfl_xor(m1, 32, 64), __shfl_xor(m2, 32, 64));
        if (hi == 0) { pm1[w][pos] = m1; pm2[w][pos] = m2; }
    }
    __syncthreads();

    if (tid < 128) {
        int p = tid;
        float M1 = pm1[0][p], M2 = pm2[0][p];
#pragma unroll
        for (int ww = 1; ww < 4; ++ww)
            top2merge(M1, M2, pm1[ww][p], pm2[ww][p]);
        int K1 = dkey(M1), K2 = dkey(M2);
        int bk = K1;
        if (M2 <= M1 + EPS_TIE) {      // rare: exact fp32 re-score, ref semantics
            int ka = min(K1, K2), kb = max(K1, K2);
            const float* xb2 = xbase + p;
            const float* ea  = emb + (ka << 6);
            const float* eb2 = emb + (kb << 6);
            float da = 0.f, db = 0.f;
#pragma unroll 4
            for (int c = 0; c < CCH; ++c) {
                float xv = xb2[c * SPA];
                da = fmaf(xv, ea[c], da);
                db = fmaf(xv, eb2[c], db);
            }
            float Da = e2s[ka] - 2.f * da;
            float Db = e2s[kb] - 2.f * db;
            bk = (Db < Da) ? kb : ka;        // tie -> lower index
        }
        bestkS[p] = bk;
        encout[b * SPA + s0 + p] = (float)bk;
        atomicAdd(&lhist[bk], 1.0f);
    }
    __syncthreads();

    {
        int tg = tid >> 7, p = tid & 127;
        int k = bestkS[p];
        const float* ee = emb + (k << 6) + tg * 32;
        float* qp = qout + b * (CCH * SPA) + s0 + p;
        float lsum = 0.f;
#pragma unroll
        for (int cb = 0; cb < 4; ++cb) {
            int oct = tg * 4 + cb;
            bf16x8 hfr = *(const bf16x8*)&xh[oct][p][0];
            bf16x8 lfr = *(const bf16x8*)&xl[oct][p][0];
#pragma unroll
            for (int jj = 0; jj < 8; ++jj) {
                float xv = bf16join(hfr[jj], lfr[jj]);
                float q  = ee[cb * 8 + jj];
                float d  = q - xv;
                lsum = fmaf(d, d, lsum);
                qp[(tg * 32 + cb * 8 + jj) * SPA] = q;
            }
        }
        for (int off = 32; off > 0; off >>= 1) lsum += __shfl_down(lsum, off, 64);
        if (lane == 0) lred[w] = lsum;
    }
    __syncthreads();
    if (tid == 0)
        unsafeAtomicAdd(loss, (lred[0] + lred[1] + lred[2] + lred[3]) * (2.5f / 14155776.f));
    if (tid < KCODES && lhist[tid] != 0.f)
        unsafeAtomicAdd(&hist[tid], lhist[tid]);
}

// ---------------- dw as one-hot MFMA GEMM: dw[k,c] = sum_n [enc==k] * x[n,c] ----------------
// 432 blocks x 512 pos. 8 waves: wave w owns m-tile codes [w*32,w*32+32), both
// n-tiles (64 ch) -> 2 x f32x16 acc in regs. x staged per 128-pos chunk as
// transposed bf16 hi/lo, XOR-swizzled: write 2-way, read conflict-free b128.
__global__ __launch_bounds__(512, 2) void vq_dw_mfma(
    const float* __restrict__ in, const float* __restrict__ encout,
    float* __restrict__ partial)
{
    __shared__ __align__(16) short xTh[2][16][64][8];   // 32KB
    __shared__ __align__(16) short xTl[2][16][64][8];   // 32KB
    __shared__ int encS[2][DWCHUNK];                    // 1KB

    int tid = threadIdx.x;
    int w = tid >> 6, lane = tid & 63;
    int blk = blockIdx.x;
    int b = (blk >= 216) ? 1 : 0;             // 216*512 = SPA: no batch straddle
    int sbase = blk * 512 - b * SPA;
    const float* xb = in + (size_t)b * (CCH * SPA);

    f32x16 acc0, acc1;
#pragma unroll
    for (int i = 0; i < 16; ++i) { acc0[i] = 0.f; acc1[i] = 0.f; }

    auto stage = [&](int buf, int t) {
        int base = sbase + t * DWCHUNK;
#pragma unroll
        for (int half = 0; half < 2; ++half) {
            int it = half * 512 + tid;        // 1024 items: (c, octet)
            int c = it >> 4, oct = it & 15;
            const float* src = xb + (size_t)c * SPA + base + oct * 8;
            float4 v0 = *(const float4*)src;
            float4 v1 = *(const float4*)(src + 4);
            float vv[8] = {v0.x, v0.y, v0.z, v0.w, v1.x, v1.y, v1.z, v1.w};
            bf16x8 hfr, lfr;
#pragma unroll
            for (int jj = 0; jj < 8; ++jj) {
                short hs, ls; bf16split(vv[jj], hs, ls);
                hfr[jj] = hs; lfr[jj] = ls;
            }
            int cx = c ^ (oct & 7);           // swizzle: write 2-way, read free
            *(bf16x8*)&xTh[buf][oct][cx][0] = hfr;
            *(bf16x8*)&xTl[buf][oct][cx][0] = lfr;
        }
        if (tid < DWCHUNK)
            encS[buf][tid] = (int)encout[blk * 512 + t * DWCHUNK + tid];
    };

    auto compute = [&](int buf) {
        int mycode = w * 32 + (lane & 31);
#pragma unroll
        for (int ks = 0; ks < 8; ++ks) {
            int kbase = ks * 16 + (lane >> 5) * 8;
            int po = kbase >> 3;              // octet index 0..15
            const int* ep = &encS[buf][kbase];
            bf16x8 afr;                       // one-hot A row (bf16 1.0 exact)
#pragma unroll
            for (int jj = 0; jj < 8; ++jj)
                afr[jj] = (ep[jj] == mycode) ? (short)0x3F80 : (short)0;
            int kx = po & 7;
            int j0 = (lane & 31) ^ kx;
            bf16x8 bh0 = *(const bf16x8*)&xTh[buf][po][j0][0];
            bf16x8 bl0 = *(const bf16x8*)&xTl[buf][po][j0][0];
            bf16x8 bh1 = *(const bf16x8*)&xTh[buf][po][32 + j0][0];
            bf16x8 bl1 = *(const bf16x8*)&xTl[buf][po][32 + j0][0];
            acc0 = __builtin_amdgcn_mfma_f32_32x32x16_bf16(afr, bh0, acc0, 0, 0, 0);
            acc0 = __builtin_amdgcn_mfma_f32_32x32x16_bf16(afr, bl0, acc0, 0, 0, 0);
            acc1 = __builtin_amdgcn_mfma_f32_32x32x16_bf16(afr, bh1, acc1, 0, 0, 0);
            acc1 = __builtin_amdgcn_mfma_f32_32x32x16_bf16(afr, bl1, acc1, 0, 0, 0);
        }
    };

    stage(0, 0);
    __syncthreads();
#pragma unroll 1
    for (int t = 0; t < 4; ++t) {
        if (t < 3) stage((t + 1) & 1, t + 1);
        compute(t & 1);
        __syncthreads();
    }

    // writeout: D map col=lane&31 (channel), row=(r&3)+8*(r>>2)+4*(lane>>5) (code)
    float* pp = partial + (size_t)blk * (CCH * KCODES);
#pragma unroll
    for (int r = 0; r < 16; ++r) {
        int code = w * 32 + (r & 3) + 8 * (r >> 2) + 4 * (lane >> 5);
        int ch = lane & 31;
        pp[code * 64 + ch]      = acc0[r];
        pp[code * 64 + 32 + ch] = acc1[r];
    }
}

__global__ __launch_bounds__(256) void vq_dw_reduce(
    const float* __restrict__ partial, float* __restrict__ dw)
{
    int i = blockIdx.x * 256 + threadIdx.x;   // 64 blocks -> 16384 outputs
    float s0 = 0.f, s1 = 0.f, s2 = 0.f, s3 = 0.f;
#pragma unroll 2
    for (int p = 0; p < DWG; p += 4) {
        s0 += partial[(size_t)(p + 0) * (CCH * KCODES) + i];
        s1 += partial[(size_t)(p + 1) * (CCH * KCODES) + i];
        s2 += partial[(size_t)(p + 2) * (CCH * KCODES) + i];
        s3 += partial[(size_t)(p + 3) * (CCH * KCODES) + i];
    }
    dw[i] = (s0 + s1) + (s2 + s3);
}

// ---------------- atomic fallback (only if ws too small for partials) ----------------
__global__ __launch_bounds__(DWTHR) void vq_dw_atomic(
    const float* __restrict__ in, const float* __restrict__ encout,
    float* __restrict__ dw)
{
    __shared__ float l[CCH * KCODES];
    int tid = threadIdx.x;
    for (int i = tid; i < CCH * KCODES; i += DWTHR) l[i] = 0.f;
    __syncthreads();
    int n = blockIdx.x * DWTHR + tid;
    int b = (n >= SPA) ? 1 : 0;
    int s = n - b * SPA;
    int k = (int)encout[n];
    const float* xp = in + b * (CCH * SPA) + s;
#pragma unroll
    for (int c = 0; c < CCH; ++c)
        atomicAdd(&l[(c << 8) + (k ^ (c & 31))], xp[c * SPA]);
    __syncthreads();
    for (int i = tid; i < CCH * KCODES; i += DWTHR) {
        int k2 = i >> 6, c = i & 63;
        unsafeAtomicAdd(&dw[i], l[(c << 8) + (k2 ^ (c & 31))]);
    }
}

// ---------------- EMA finalize, fused: weights + divide ----------------
__global__ __launch_bounds__(1024) void vq_ema(
    const float* __restrict__ csize, const float* __restrict__ emaw,
    const float* __restrict__ hist, const float* __restrict__ dw,
    float* __restrict__ embo)
{
    __shared__ float red[KCODES];
    __shared__ float wsm[KCODES];
    int t = threadIdx.x;
    float ncs = 0.f;
    if (t < KCODES) { ncs = 0.99f * csize[t] + 0.01f * hist[t]; red[t] = ncs; }
    __syncthreads();
    for (int off = 128; off > 0; off >>= 1) {
        if (t < off) red[t] += red[t + off];
        __syncthreads();
    }
    float nsum = red[0];
    if (t < KCODES) wsm[t] = (ncs + 1e-5f) / (nsum + 256.f * 1e-5f) * nsum;
    __syncthreads();
    for (int i = t; i < CCH * KCODES; i += 1024) {
        float nw = fmaf(0.01f, dw[i], 0.99f * emaw[i]);
        embo[i] = nw / wsm[i >> 6];
    }
}

extern "C" void kernel_launch(void* const* d_in, const int* in_sizes, int n_in,
                              void* d_out, int out_size, void* d_ws, size_t ws_size,
                              hipStream_t stream)
{
    const float* in   = (const float*)d_in[0];
    const float* emb  = (const float*)d_in[1];
    const float* cs   = (const float*)d_in[2];
    const float* emaw = (const float*)d_in[3];

    float* out  = (float*)d_out;
    float* qout = out;                         // 14,155,776
    float* loss = out + NELEM;                 // 1
    float* enc  = loss + 1;                    // 221,184
    float* hist = enc + NPOS;                  // 256  (encodings_sum output)
    float* embo = hist + KCODES;               // 16,384

    float* en2     = (float*)d_ws;             // 256
    float* dw      = en2 + KCODES;             // 16,384
    float* fragH   = dw + CCH * KCODES;        // 8,192 floats (32KB of bf16x8)
    float* fragL   = fragH + 8192;             // 8,192
    float* partial = fragL + 8192;             // 432 * 16,384

    size_t need = (size_t)(KCODES + CCH * KCODES + 16384) * 4
                + (size_t)DWG * CCH * KCODES * 4;
    bool use_part = (ws_size >= need);         // constant per session -> graph-safe

    vq_init<<<dim3(64), dim3(256), 0, stream>>>(emb, en2, dw, hist, loss, fragH, fragL);
    vq_argmin_mfma<<<dim3(1728), dim3(256), 0, stream>>>(in, emb, en2, fragH, fragL,
                                                         qout, enc, hist, loss);
    if (use_part) {
        vq_dw_mfma<<<dim3(DWG), dim3(512), 0, stream>>>(in, enc, partial);
        vq_dw_reduce<<<dim3(64), dim3(256), 0, stream>>>(partial, dw);
    } else {
        vq_dw_atomic<<<dim3(DWBLK), dim3(DWTHR), 0, stream>>>(in, enc, dw);
    }
    vq_ema<<<dim3(1), dim3(1024), 0, stream>>>(cs, emaw, hist, dw, embo);
}